// Round 3
// baseline (1228.671 us; speedup 1.0000x reference)
//
#include <hip/hip_runtime.h>
#include <hip/hip_bf16.h>

// Shapes fixed by the reference: b=1, c=512, t=16, h=w=32
#define CCH   512
#define NPOS  16384
#define NTOK  1024
#define NFRM  16
#define NGRP  32
#define GSZ   (CCH / NGRP)
#define GELEM (GSZ * NPOS)

typedef unsigned short u16;
typedef unsigned int   u32;

__device__ __forceinline__ float bf2f(u16 u) {
    return __uint_as_float(((u32)u) << 16);
}
__device__ __forceinline__ u16 f2bf(float f) {
    u32 u = __float_as_uint(f);
    u = (u + 0x7fffu + ((u >> 16) & 1u)) >> 16;
    return (u16)u;
}
// polymorphic scalar load: the same buffer viewed as bf16 or f32 per flag
__device__ __forceinline__ float ldx(const void* p, size_t i, bool f32m) {
    return f32m ? ((const float*)p)[i] : bf2f(((const u16*)p)[i]);
}

// ------------------------------------------------------------ dtype detect
// If x is f32, the low u16 of each 32-bit word is mantissa junk: ~22% of
// patterns have bf16-exponent >= 0xC8. If x is bf16, those u16s are sane
// N(0,1) values (exp <= ~0x82) -> count 0.
__launch_bounds__(256)
__global__ void detect_dtype(const u32* __restrict__ x32, u32* __restrict__ flag) {
    __shared__ int cnt;
    if (threadIdx.x == 0) cnt = 0;
    __syncthreads();
    int c = 0;
    for (int i = threadIdx.x; i < 4096; i += 256) {
        u32 v = x32[i] & 0xFFFFu;
        u32 e = (v >> 7) & 0xFFu;
        if (e >= 0xC8u) c++;
    }
    atomicAdd(&cnt, c);
    __syncthreads();
    if (threadIdx.x == 0) *flag = (cnt > 64) ? 1u : 0u;
}

// canonicalize a tensor to bf16
__launch_bounds__(256)
__global__ void conv_bf16(const void* __restrict__ src, u16* __restrict__ dst,
                          int n, const u32* __restrict__ flag) {
    bool f32m = *flag != 0u;
    int i = blockIdx.x * 256 + threadIdx.x;
    if (i < n) dst[i] = f32m ? f2bf(((const float*)src)[i]) : ((const u16*)src)[i];
}

// ---------------------------------------------------------------- GroupNorm
__launch_bounds__(256)
__global__ void gn_stats(const void* __restrict__ x, float2* __restrict__ stats,
                         const u32* __restrict__ flag) {
    __shared__ float sm[8];
    bool f32m = *flag != 0u;
    int g = blockIdx.x;
    float s = 0.f, ss = 0.f;
    if (f32m) {
        const float4* p = (const float4*)((const float*)x + (size_t)g * GELEM);
        for (int i = threadIdx.x; i < GELEM / 4; i += 256) {
            float4 u = p[i];
            s  += u.x + u.y + u.z + u.w;
            ss += u.x * u.x + u.y * u.y + u.z * u.z + u.w * u.w;
        }
    } else {
        const ushort4* p = (const ushort4*)((const u16*)x + (size_t)g * GELEM);
        for (int i = threadIdx.x; i < GELEM / 4; i += 256) {
            ushort4 u = p[i];
            float a = bf2f(u.x), b = bf2f(u.y), c = bf2f(u.z), d = bf2f(u.w);
            s  += a + b + c + d;
            ss += a * a + b * b + c * c + d * d;
        }
    }
    int lane = threadIdx.x & 63, w = threadIdx.x >> 6;
    float t = s;
    #pragma unroll
    for (int o = 32; o > 0; o >>= 1) t += __shfl_down(t, o, 64);
    if (lane == 0) sm[w] = t;
    t = ss;
    #pragma unroll
    for (int o = 32; o > 0; o >>= 1) t += __shfl_down(t, o, 64);
    if (lane == 0) sm[4 + w] = t;
    __syncthreads();
    if (threadIdx.x == 0) {
        float sum = sm[0] + sm[1] + sm[2] + sm[3];
        float sq  = sm[4] + sm[5] + sm[6] + sm[7];
        float mean = sum * (1.0f / (float)GELEM);
        float var  = fmaxf(sq * (1.0f / (float)GELEM) - mean * mean, 0.0f);
        stats[g] = make_float2(mean, rsqrtf(var + 1e-6f));
    }
}

// per-channel affine: xn = x*sc + sh
__launch_bounds__(256)
__global__ void gn_coef(const float2* __restrict__ stats, const void* __restrict__ gamma,
                        const void* __restrict__ beta, float2* __restrict__ coef,
                        const u32* __restrict__ flag) {
    bool f32m = *flag != 0u;
    int c = blockIdx.x * 256 + threadIdx.x;
    if (c < CCH) {
        float2 st = stats[c >> 4];
        float g = ldx(gamma, c, f32m), b = ldx(beta, c, f32m);
        float sc = st.y * g;
        coef[c] = make_float2(sc, b - st.x * sc);
    }
}

// ------------------------------------------------- shared 64x64x16 tile GEMM core
#define GEMM_INNER()                                                     \
    _Pragma("unroll")                                                    \
    for (int k = 0; k < 16; ++k) {                                       \
        float4 av = *(const float4*)&As[k][ty * 4];                      \
        float4 bv = *(const float4*)&Bs[k][tx * 4];                      \
        float a0 = av.x, a1 = av.y, a2 = av.z, a3 = av.w;                \
        float b0 = bv.x, b1 = bv.y, b2 = bv.z, b3 = bv.w;                \
        acc[0][0] += a0 * b0; acc[0][1] += a0 * b1;                      \
        acc[0][2] += a0 * b2; acc[0][3] += a0 * b3;                      \
        acc[1][0] += a1 * b0; acc[1][1] += a1 * b1;                      \
        acc[1][2] += a1 * b2; acc[1][3] += a1 * b3;                      \
        acc[2][0] += a2 * b0; acc[2][1] += a2 * b1;                      \
        acc[2][2] += a2 * b2; acc[2][3] += a2 * b3;                      \
        acc[3][0] += a3 * b0; acc[3][1] += a3 * b1;                      \
        acc[3][2] += a3 * b2; acc[3][3] += a3 * b3;                      \
    }

// q/k/v projection with GN fused into B staging. W is canonical bf16.
// C[m,n] = sum_c W[m,c]*(x[c,n]*sc[c]+sh[c]) + bias[m]   (M=512,N=16384,K=512)
__launch_bounds__(256)
__global__ void gemm_qkv(const u16* __restrict__ W, const u16* __restrict__ bias,
                         const void* __restrict__ x, const float2* __restrict__ coef,
                         u16* __restrict__ Cdst, const u32* __restrict__ flag) {
    const int K = CCH, N = NPOS;
    bool f32m = *flag != 0u;
    __shared__ float As[16][68];
    __shared__ float Bs[16][68];
    int tid = threadIdx.x;
    int n0 = blockIdx.x * 64, m0 = blockIdx.y * 64;
    int tx = tid & 15, ty = tid >> 4;
    float acc[4][4] = {};
    for (int kk = 0; kk < K; kk += 16) {
        #pragma unroll
        for (int i = 0; i < 4; ++i) {
            int li = i * 256 + tid;
            int ka = li & 15, ma = li >> 4;
            As[ka][ma] = bf2f(W[(size_t)(m0 + ma) * K + kk + ka]);
            int nb = li & 63, kb = li >> 6;
            int c = kk + kb;
            float2 cf = coef[c];
            Bs[kb][nb] = ldx(x, (size_t)c * N + n0 + nb, f32m) * cf.x + cf.y;
        }
        __syncthreads();
        GEMM_INNER()
        __syncthreads();
    }
    #pragma unroll
    for (int i = 0; i < 4; ++i) {
        int m = m0 + ty * 4 + i;
        float bv = bf2f(bias[m]);
        #pragma unroll
        for (int j = 0; j < 4; ++j)
            Cdst[(size_t)m * N + n0 + tx * 4 + j] = f2bf(acc[i][j] + bv);
    }
}

// final projection + residual: y = Wo*O + bo + x   (store in true dtype)
__launch_bounds__(256)
__global__ void gemm_out(const u16* __restrict__ W, const u16* __restrict__ bias,
                         const u16* __restrict__ Bsrc, const void* __restrict__ x,
                         void* __restrict__ y, const u32* __restrict__ flag) {
    const int K = CCH, N = NPOS;
    bool f32m = *flag != 0u;
    __shared__ float As[16][68];
    __shared__ float Bs[16][68];
    int tid = threadIdx.x;
    int n0 = blockIdx.x * 64, m0 = blockIdx.y * 64;
    int tx = tid & 15, ty = tid >> 4;
    float acc[4][4] = {};
    for (int kk = 0; kk < K; kk += 16) {
        #pragma unroll
        for (int i = 0; i < 4; ++i) {
            int li = i * 256 + tid;
            int ka = li & 15, ma = li >> 4;
            As[ka][ma] = bf2f(W[(size_t)(m0 + ma) * K + kk + ka]);
            int nb = li & 63, kb = li >> 6;
            Bs[kb][nb] = bf2f(Bsrc[(size_t)(kk + kb) * N + n0 + nb]);
        }
        __syncthreads();
        GEMM_INNER()
        __syncthreads();
    }
    #pragma unroll
    for (int i = 0; i < 4; ++i) {
        int m = m0 + ty * 4 + i;
        float bv = bf2f(bias[m]);
        #pragma unroll
        for (int j = 0; j < 4; ++j) {
            size_t idx = (size_t)m * N + n0 + tx * 4 + j;
            float r = acc[i][j] + bv + ldx(x, idx, f32m);
            if (f32m) ((float*)y)[idx] = r;
            else      ((u16*)y)[idx]   = f2bf(r);
        }
    }
}

// scores: S[zi,i,j] = scale * sum_c q[c,f*1024+i]*k[c,f*1024+j], f=f0+zi
__launch_bounds__(256)
__global__ void gemm_scores(const u16* __restrict__ q, const u16* __restrict__ kptr,
                            float* __restrict__ S, int f0) {
    const int K = CCH;
    int f = f0 + blockIdx.z;
    size_t off = (size_t)f * NTOK;
    __shared__ float As[16][68];
    __shared__ float Bs[16][68];
    int tid = threadIdx.x;
    int n0 = blockIdx.x * 64, m0 = blockIdx.y * 64;
    int tx = tid & 15, ty = tid >> 4;
    float acc[4][4] = {};
    for (int kk = 0; kk < K; kk += 16) {
        #pragma unroll
        for (int i = 0; i < 4; ++i) {
            int li = i * 256 + tid;
            int col = li & 63, kr = li >> 6;
            As[kr][col] = bf2f(q[(size_t)(kk + kr) * NPOS + off + m0 + col]);
            Bs[kr][col] = bf2f(kptr[(size_t)(kk + kr) * NPOS + off + n0 + col]);
        }
        __syncthreads();
        GEMM_INNER()
        __syncthreads();
    }
    float* Srow = S + (size_t)blockIdx.z * NTOK * NTOK;
    const float scale = 0.044194173824159216f;  // 512^-0.5
    #pragma unroll
    for (int i = 0; i < 4; ++i)
        #pragma unroll
        for (int j = 0; j < 4; ++j)
            Srow[(size_t)(m0 + ty * 4 + i) * NTOK + n0 + tx * 4 + j] = acc[i][j] * scale;
}

// softmax over last axis, one block per row of 1024
__launch_bounds__(256)
__global__ void softmax_rows(float* __restrict__ S) {
    __shared__ float sm[8];
    float* p = S + (size_t)blockIdx.x * NTOK;
    int tid = threadIdx.x;
    float v0 = p[tid], v1 = p[tid + 256], v2 = p[tid + 512], v3 = p[tid + 768];
    float m = fmaxf(fmaxf(v0, v1), fmaxf(v2, v3));
    int lane = tid & 63, w = tid >> 6;
    #pragma unroll
    for (int o = 32; o > 0; o >>= 1) m = fmaxf(m, __shfl_down(m, o, 64));
    if (lane == 0) sm[w] = m;
    __syncthreads();
    m = fmaxf(fmaxf(sm[0], sm[1]), fmaxf(sm[2], sm[3]));
    v0 = __expf(v0 - m); v1 = __expf(v1 - m);
    v2 = __expf(v2 - m); v3 = __expf(v3 - m);
    float s = v0 + v1 + v2 + v3;
    #pragma unroll
    for (int o = 32; o > 0; o >>= 1) s += __shfl_down(s, o, 64);
    if (lane == 0) sm[4 + w] = s;
    __syncthreads();
    s = sm[4] + sm[5] + sm[6] + sm[7];
    float inv = 1.0f / s;
    p[tid] = v0 * inv; p[tid + 256] = v1 * inv;
    p[tid + 512] = v2 * inv; p[tid + 768] = v3 * inv;
}

// O[c,f*1024+i] = sum_j v[c,f*1024+j]*P[zi,i,j], f=f0+zi  (M=512,N=1024,K=1024)
__launch_bounds__(256)
__global__ void gemm_pv(const u16* __restrict__ v, const float* __restrict__ S,
                        u16* __restrict__ O, int f0) {
    const int K = NTOK;
    int f = f0 + blockIdx.z;
    size_t off = (size_t)f * NTOK;
    const float* P = S + (size_t)blockIdx.z * NTOK * NTOK;
    __shared__ float As[16][68];
    __shared__ float Bs[16][68];
    int tid = threadIdx.x;
    int n0 = blockIdx.x * 64, m0 = blockIdx.y * 64;
    int tx = tid & 15, ty = tid >> 4;
    float acc[4][4] = {};
    for (int kk = 0; kk < K; kk += 16) {
        #pragma unroll
        for (int i = 0; i < 4; ++i) {
            int li = i * 256 + tid;
            int ka = li & 15, ma = li >> 4;
            As[ka][ma] = bf2f(v[(size_t)(m0 + ma) * NPOS + off + kk + ka]);
            Bs[ka][ma] = P[(size_t)(n0 + ma) * NTOK + kk + ka];
        }
        __syncthreads();
        GEMM_INNER()
        __syncthreads();
    }
    #pragma unroll
    for (int i = 0; i < 4; ++i)
        #pragma unroll
        for (int j = 0; j < 4; ++j)
            O[(size_t)(m0 + ty * 4 + i) * NPOS + off + n0 + tx * 4 + j] = f2bf(acc[i][j]);
}

// ---------------------------------------------------------------- launcher
extern "C" void kernel_launch(void* const* d_in, const int* in_sizes, int n_in,
                              void* d_out, int out_size, void* d_ws, size_t ws_size,
                              hipStream_t stream) {
    const void* x   = d_in[0];
    const void* gam = d_in[1];
    const void* bet = d_in[2];

    // Workspace layout:
    //   [0,4096)      coef            [4096,4352)  stats        [4352,..) flag
    //   [8192, +2Mi)  canonical bf16 weights wq,wk,wv,wo (512KiB each)
    //   [.., +4KiB)   canonical bf16 biases  bq,bk,bv,bo (1KiB each)
    //   [4Mi,  +16Mi) qbuf (reused as attention output)
    //   [20Mi, +16Mi) kbuf
    //   [36Mi, +16Mi) vbuf
    //   [52Mi, ...)   sbuf: 64MiB batched, or 4MiB per-frame fallback
    char* ws = (char*)d_ws;
    float2* coef  = (float2*)(ws);
    float2* stats = (float2*)(ws + 4096);
    u32*    flag  = (u32*)(ws + 4352);
    u16* cw[4] = { (u16*)(ws + 8192),           (u16*)(ws + 8192 +  524288ull),
                   (u16*)(ws + 8192 + 1048576ull), (u16*)(ws + 8192 + 1572864ull) };
    u16* cb[4] = { (u16*)(ws + 2105344ull),        (u16*)(ws + 2105344ull + 1024),
                   (u16*)(ws + 2105344ull + 2048), (u16*)(ws + 2105344ull + 3072) };
    u16*  qbuf = (u16*)(ws + (4ull << 20));
    u16*  kbuf = (u16*)(ws + (20ull << 20));
    u16*  vbuf = (u16*)(ws + (36ull << 20));
    float* sbuf = (float*)(ws + (52ull << 20));
    u16*  obuf = qbuf;

    const size_t need_big = (52ull << 20) + (64ull << 20) + 4096;
    const bool big = ws_size >= need_big;

    detect_dtype<<<1, 256, 0, stream>>>((const u32*)x, flag);

    // canonicalize weights & biases to bf16
    for (int i = 0; i < 4; ++i) {
        conv_bf16<<<(262144 + 255) / 256, 256, 0, stream>>>(d_in[3 + 2 * i], cw[i], 262144, flag);
        conv_bf16<<<2, 256, 0, stream>>>(d_in[4 + 2 * i], cb[i], 512, flag);
    }

    gn_stats<<<NGRP, 256, 0, stream>>>(x, stats, flag);
    gn_coef<<<2, 256, 0, stream>>>(stats, gam, bet, coef, flag);

    dim3 gproj(NPOS / 64, CCH / 64);                  // (256, 8)
    gemm_qkv<<<gproj, 256, 0, stream>>>(cw[0], cb[0], x, coef, qbuf, flag);
    gemm_qkv<<<gproj, 256, 0, stream>>>(cw[1], cb[1], x, coef, kbuf, flag);
    gemm_qkv<<<gproj, 256, 0, stream>>>(cw[2], cb[2], x, coef, vbuf, flag);

    if (big) {
        dim3 gsc(NTOK / 64, NTOK / 64, NFRM);
        gemm_scores<<<gsc, 256, 0, stream>>>(qbuf, kbuf, sbuf, 0);
        softmax_rows<<<NFRM * NTOK, 256, 0, stream>>>(sbuf);
        dim3 gpv(NTOK / 64, CCH / 64, NFRM);
        gemm_pv<<<gpv, 256, 0, stream>>>(vbuf, sbuf, obuf, 0);
    } else {
        for (int f = 0; f < NFRM; ++f) {
            dim3 gsc(NTOK / 64, NTOK / 64, 1);
            gemm_scores<<<gsc, 256, 0, stream>>>(qbuf, kbuf, sbuf, f);
            softmax_rows<<<NTOK, 256, 0, stream>>>(sbuf);
            dim3 gpv(NTOK / 64, CCH / 64, 1);
            gemm_pv<<<gpv, 256, 0, stream>>>(vbuf, sbuf, obuf, f);
        }
    }

    gemm_out<<<gproj, 256, 0, stream>>>(cw[3], cb[3], obuf, x, d_out, flag);
}

// Round 4
// 422.517 us; speedup vs baseline: 2.9080x; 2.9080x over previous
//
#include <hip/hip_runtime.h>
#include <hip/hip_bf16.h>

// Shapes fixed by the reference: b=1, c=512, t=16, h=w=32
#define CCH   512
#define NPOS  16384
#define NTOK  1024
#define NFRM  16
#define NGRP  32
#define GSZ   (CCH / NGRP)
#define GELEM (GSZ * NPOS)

typedef unsigned short u16;
typedef unsigned int   u32;
typedef __attribute__((ext_vector_type(8))) short  short8;
typedef __attribute__((ext_vector_type(4))) float  floatx4;

__device__ __forceinline__ float bf2f(u16 u) {
    return __uint_as_float(((u32)u) << 16);
}
__device__ __forceinline__ u16 f2bf(float f) {
    u32 u = __float_as_uint(f);
    u = (u + 0x7fffu + ((u >> 16) & 1u)) >> 16;
    return (u16)u;
}
__device__ __forceinline__ float ldx(const void* p, size_t i, bool f32m) {
    return f32m ? ((const float*)p)[i] : bf2f(((const u16*)p)[i]);
}

// ------------------------------------------------------------ dtype detect
__launch_bounds__(256)
__global__ void detect_dtype(const u32* __restrict__ x32, u32* __restrict__ flag) {
    __shared__ int cnt;
    if (threadIdx.x == 0) cnt = 0;
    __syncthreads();
    int c = 0;
    for (int i = threadIdx.x; i < 4096; i += 256) {
        u32 v = x32[i] & 0xFFFFu;
        u32 e = (v >> 7) & 0xFFu;
        if (e >= 0xC8u) c++;
    }
    atomicAdd(&cnt, c);
    __syncthreads();
    if (threadIdx.x == 0) *flag = (cnt > 64) ? 1u : 0u;
}

__launch_bounds__(256)
__global__ void conv_bf16(const void* __restrict__ src, u16* __restrict__ dst,
                          int n, const u32* __restrict__ flag) {
    bool f32m = *flag != 0u;
    int i = blockIdx.x * 256 + threadIdx.x;
    if (i < n) dst[i] = f32m ? f2bf(((const float*)src)[i]) : ((const u16*)src)[i];
}

// ---------------------------------------------------------------- GroupNorm
__launch_bounds__(256)
__global__ void gn_stats(const void* __restrict__ x, float2* __restrict__ stats,
                         const u32* __restrict__ flag) {
    __shared__ float sm[8];
    bool f32m = *flag != 0u;
    int g = blockIdx.x;
    float s = 0.f, ss = 0.f;
    if (f32m) {
        const float4* p = (const float4*)((const float*)x + (size_t)g * GELEM);
        for (int i = threadIdx.x; i < GELEM / 4; i += 256) {
            float4 u = p[i];
            s  += u.x + u.y + u.z + u.w;
            ss += u.x * u.x + u.y * u.y + u.z * u.z + u.w * u.w;
        }
    } else {
        const ushort4* p = (const ushort4*)((const u16*)x + (size_t)g * GELEM);
        for (int i = threadIdx.x; i < GELEM / 4; i += 256) {
            ushort4 u = p[i];
            float a = bf2f(u.x), b = bf2f(u.y), c = bf2f(u.z), d = bf2f(u.w);
            s  += a + b + c + d;
            ss += a * a + b * b + c * c + d * d;
        }
    }
    int lane = threadIdx.x & 63, w = threadIdx.x >> 6;
    float t = s;
    #pragma unroll
    for (int o = 32; o > 0; o >>= 1) t += __shfl_down(t, o, 64);
    if (lane == 0) sm[w] = t;
    t = ss;
    #pragma unroll
    for (int o = 32; o > 0; o >>= 1) t += __shfl_down(t, o, 64);
    if (lane == 0) sm[4 + w] = t;
    __syncthreads();
    if (threadIdx.x == 0) {
        float sum = sm[0] + sm[1] + sm[2] + sm[3];
        float sq  = sm[4] + sm[5] + sm[6] + sm[7];
        float mean = sum * (1.0f / (float)GELEM);
        float var  = fmaxf(sq * (1.0f / (float)GELEM) - mean * mean, 0.0f);
        stats[g] = make_float2(mean, rsqrtf(var + 1e-6f));
    }
}

__launch_bounds__(256)
__global__ void gn_coef(const float2* __restrict__ stats, const void* __restrict__ gamma,
                        const void* __restrict__ beta, float2* __restrict__ coef,
                        const u32* __restrict__ flag) {
    bool f32m = *flag != 0u;
    int c = blockIdx.x * 256 + threadIdx.x;
    if (c < CCH) {
        float2 st = stats[c >> 4];
        float g = ldx(gamma, c, f32m), b = ldx(beta, c, f32m);
        float sc = st.y * g;
        coef[c] = make_float2(sc, b - st.x * sc);
    }
}

// GN-apply + transpose: x [c][pos] (poly) -> xn_t [pos][c] (bf16)
__launch_bounds__(256)
__global__ void gn_apply_t(const void* __restrict__ x, const float2* __restrict__ coef,
                           u16* __restrict__ xt, const u32* __restrict__ flag) {
    bool f32m = *flag != 0u;
    __shared__ float tile[64][65];
    int p0 = blockIdx.x * 64, c0 = blockIdx.y * 64;
    int lane = threadIdx.x & 63, rg = threadIdx.x >> 6;
    #pragma unroll 4
    for (int i = 0; i < 16; ++i) {
        int row = rg * 16 + i;          // channel offset within tile
        int c = c0 + row;
        float2 cf = coef[c];
        float v = ldx(x, (size_t)c * NPOS + p0 + lane, f32m);
        tile[row][lane] = v * cf.x + cf.y;
    }
    __syncthreads();
    #pragma unroll 4
    for (int i = 0; i < 16; ++i) {
        int prow = rg * 16 + i;         // position offset within tile
        xt[(size_t)(p0 + prow) * CCH + c0 + lane] = f2bf(tile[lane][prow]);
    }
}

// --------------------------------------------------------- MFMA TN GEMM
// C[m][n] = sum_k A[m*lda+k] * B[n*ldb+k]   (A,B bf16, K-contiguous rows)
// 128x128 tile / workgroup (4 waves, 64x64 each), BK=32, 16x16x32 bf16 MFMA.
#define EPI_QK  0   // C bf16, += bias[n]
#define EPI_V   1   // C bf16, += bias[m]
#define EPI_SC  2   // C f32,  *= scale
#define EPI_PV  3   // C bf16
#define EPI_OUT 4   // C poly, += bias[m] + resid[idx]

#define LDS_ROW 40  // BK(32) + 8 pad, in bf16 elements

template<int EPI>
__launch_bounds__(256)
__global__ void mfma_gemm(const u16* __restrict__ A, const u16* __restrict__ B,
                          void* __restrict__ C, const u16* __restrict__ bias,
                          const void* __restrict__ resid, const u32* __restrict__ flag,
                          int lda, int ldb, int ldc, int K,
                          long aFS, long bFS, long cFS) {
    __shared__ u16 As[128 * LDS_ROW];
    __shared__ u16 Bs[128 * LDS_ROW];
    const int tid = threadIdx.x;
    const int f = blockIdx.z;
    const u16* Ab = A + (size_t)f * aFS + (size_t)blockIdx.y * 128 * lda;
    const u16* Bb = B + (size_t)f * bFS + (size_t)blockIdx.x * 128 * ldb;

    const int srow = tid >> 2;            // 0..63
    const int sch  = (tid & 3) * 8;       // 0,8,16,24 (bf16 elems)

    const int wave = tid >> 6, lane = tid & 63;
    const int wm = (wave >> 1) * 64, wn = (wave & 1) * 64;
    const int l15 = lane & 15, quad = lane >> 4;

    floatx4 acc[4][4] = {};

    for (int kk = 0; kk < K; kk += 32) {
        uint4 a0 = *(const uint4*)(Ab + (size_t)srow * lda + kk + sch);
        uint4 a1 = *(const uint4*)(Ab + (size_t)(srow + 64) * lda + kk + sch);
        uint4 b0 = *(const uint4*)(Bb + (size_t)srow * ldb + kk + sch);
        uint4 b1 = *(const uint4*)(Bb + (size_t)(srow + 64) * ldb + kk + sch);
        __syncthreads();
        *(uint4*)&As[srow * LDS_ROW + sch]        = a0;
        *(uint4*)&As[(srow + 64) * LDS_ROW + sch] = a1;
        *(uint4*)&Bs[srow * LDS_ROW + sch]        = b0;
        *(uint4*)&Bs[(srow + 64) * LDS_ROW + sch] = b1;
        __syncthreads();
        short8 af[4], bf[4];
        #pragma unroll
        for (int mi = 0; mi < 4; ++mi)
            af[mi] = *(const short8*)&As[(wm + mi * 16 + l15) * LDS_ROW + quad * 8];
        #pragma unroll
        for (int ni = 0; ni < 4; ++ni)
            bf[ni] = *(const short8*)&Bs[(wn + ni * 16 + l15) * LDS_ROW + quad * 8];
        #pragma unroll
        for (int mi = 0; mi < 4; ++mi)
            #pragma unroll
            for (int ni = 0; ni < 4; ++ni)
                acc[mi][ni] = __builtin_amdgcn_mfma_f32_16x16x32_bf16(
                    af[mi], bf[ni], acc[mi][ni], 0, 0, 0);
    }

    const bool f32m = (EPI == EPI_OUT) ? (*flag != 0u) : false;
    const int m_base = blockIdx.y * 128 + wm;
    const int n_base = blockIdx.x * 128 + wn;
    const float scale = 0.044194173824159216f;  // 512^-0.5

    #pragma unroll
    for (int mi = 0; mi < 4; ++mi) {
        #pragma unroll
        for (int ni = 0; ni < 4; ++ni) {
            int n = n_base + ni * 16 + l15;
            float bn = (EPI == EPI_QK) ? bf2f(bias[n]) : 0.0f;
            #pragma unroll
            for (int r = 0; r < 4; ++r) {
                int m = m_base + mi * 16 + quad * 4 + r;
                float v = acc[mi][ni][r];
                size_t idx = (size_t)f * cFS + (size_t)m * ldc + n;
                if (EPI == EPI_QK) {
                    ((u16*)C)[idx] = f2bf(v + bn);
                } else if (EPI == EPI_V) {
                    ((u16*)C)[idx] = f2bf(v + bf2f(bias[m]));
                } else if (EPI == EPI_SC) {
                    ((float*)C)[idx] = v * scale;
                } else if (EPI == EPI_PV) {
                    ((u16*)C)[idx] = f2bf(v);
                } else {  // EPI_OUT
                    float r2 = v + bf2f(bias[m]) + ldx(resid, idx, f32m);
                    if (f32m) ((float*)C)[idx] = r2;
                    else      ((u16*)C)[idx]   = f2bf(r2);
                }
            }
        }
    }
}

// softmax over rows of 1024 f32, writing bf16 P in-place at row start
__launch_bounds__(256)
__global__ void softmax_rows_bf16(float* __restrict__ S) {
    __shared__ float sm[8];
    float* p = S + (size_t)blockIdx.x * NTOK;
    u16* pb = (u16*)p;
    int tid = threadIdx.x;
    float v0 = p[tid], v1 = p[tid + 256], v2 = p[tid + 512], v3 = p[tid + 768];
    float m = fmaxf(fmaxf(v0, v1), fmaxf(v2, v3));
    int lane = tid & 63, w = tid >> 6;
    #pragma unroll
    for (int o = 32; o > 0; o >>= 1) m = fmaxf(m, __shfl_down(m, o, 64));
    if (lane == 0) sm[w] = m;
    __syncthreads();
    m = fmaxf(fmaxf(sm[0], sm[1]), fmaxf(sm[2], sm[3]));
    v0 = __expf(v0 - m); v1 = __expf(v1 - m);
    v2 = __expf(v2 - m); v3 = __expf(v3 - m);
    float s = v0 + v1 + v2 + v3;
    #pragma unroll
    for (int o = 32; o > 0; o >>= 1) s += __shfl_down(s, o, 64);
    if (lane == 0) sm[4 + w] = s;
    __syncthreads();
    s = sm[4] + sm[5] + sm[6] + sm[7];
    float inv = 1.0f / s;
    __syncthreads();   // all reads complete before bf16 overwrite
    pb[tid]       = f2bf(v0 * inv);
    pb[tid + 256] = f2bf(v1 * inv);
    pb[tid + 512] = f2bf(v2 * inv);
    pb[tid + 768] = f2bf(v3 * inv);
}

// ---------------------------------------------------------------- launcher
extern "C" void kernel_launch(void* const* d_in, const int* in_sizes, int n_in,
                              void* d_out, int out_size, void* d_ws, size_t ws_size,
                              hipStream_t stream) {
    const void* x   = d_in[0];
    const void* gam = d_in[1];
    const void* bet = d_in[2];

    // Workspace layout:
    //   [0,4K)  coef   [4K,4.25K) stats  [4352) flag
    //   [8K, +2MiB)   canonical bf16 weights wq,wk,wv,wo
    //   [2105344, +4KiB) canonical bf16 biases
    //   [4Mi)   xn_t (16Mi)  -- reused as obuf after V-projection
    //   [20Mi)  qt   (16Mi)
    //   [36Mi)  kt   (16Mi)
    //   [52Mi)  vt   (16Mi)
    //   [68Mi)  sbuf: 64Mi f32 (big) or 4Mi (per-frame fallback)
    char* ws = (char*)d_ws;
    float2* coef  = (float2*)(ws);
    float2* stats = (float2*)(ws + 4096);
    u32*    flag  = (u32*)(ws + 4352);
    u16* cw[4] = { (u16*)(ws + 8192),              (u16*)(ws + 8192 +  524288ull),
                   (u16*)(ws + 8192 + 1048576ull), (u16*)(ws + 8192 + 1572864ull) };
    u16* cb[4] = { (u16*)(ws + 2105344ull),        (u16*)(ws + 2105344ull + 1024),
                   (u16*)(ws + 2105344ull + 2048), (u16*)(ws + 2105344ull + 3072) };
    u16*  xnt  = (u16*)(ws + (4ull  << 20));
    u16*  qt   = (u16*)(ws + (20ull << 20));
    u16*  kt   = (u16*)(ws + (36ull << 20));
    u16*  vt   = (u16*)(ws + (52ull << 20));
    float* sbuf = (float*)(ws + (68ull << 20));
    u16*  obuf = xnt;

    const size_t need_big = (68ull << 20) + (64ull << 20) + 4096;
    const bool big = ws_size >= need_big;

    detect_dtype<<<1, 256, 0, stream>>>((const u32*)x, flag);
    for (int i = 0; i < 4; ++i) {
        conv_bf16<<<1024, 256, 0, stream>>>(d_in[3 + 2 * i], cw[i], 262144, flag);
        conv_bf16<<<2, 256, 0, stream>>>(d_in[4 + 2 * i], cb[i], 512, flag);
    }
    gn_stats<<<NGRP, 256, 0, stream>>>(x, stats, flag);
    gn_coef<<<2, 256, 0, stream>>>(stats, gam, bet, coef, flag);
    gn_apply_t<<<dim3(NPOS / 64, CCH / 64), 256, 0, stream>>>(x, coef, xnt, flag);

    // q,k: C[pos][cout], A=xn_t (lda=512), B=W (ldb=512), ldc=512
    dim3 gqk(CCH / 128, NPOS / 128, 1);   // (4, 128)
    mfma_gemm<EPI_QK><<<gqk, 256, 0, stream>>>(xnt, cw[0], qt, cb[0], nullptr, flag,
                                               CCH, CCH, CCH, CCH, 0, 0, 0);
    mfma_gemm<EPI_QK><<<gqk, 256, 0, stream>>>(xnt, cw[1], kt, cb[1], nullptr, flag,
                                               CCH, CCH, CCH, CCH, 0, 0, 0);
    // v: C[cout][pos], A=Wv (lda=512), B=xn_t (ldb=512), ldc=16384
    dim3 gv(NPOS / 128, CCH / 128, 1);    // (128, 4)
    mfma_gemm<EPI_V><<<gv, 256, 0, stream>>>(cw[2], xnt, vt, cb[2], nullptr, flag,
                                             CCH, CCH, NPOS, CCH, 0, 0, 0);

    if (big) {
        // scores: per frame, C f32 [i][j], A=qt, B=kt
        dim3 gsc(NTOK / 128, NTOK / 128, NFRM);   // (8, 8, 16)
        mfma_gemm<EPI_SC><<<gsc, 256, 0, stream>>>(qt, kt, sbuf, nullptr, nullptr, flag,
                                                   CCH, CCH, NTOK, CCH,
                                                   NTOK * CCH, NTOK * CCH, (long)NTOK * NTOK);
        softmax_rows_bf16<<<NFRM * NTOK, 256, 0, stream>>>(sbuf);
        // pv: A=P (bf16 view of sbuf, lda=2048), B=vt rows=c (ldb=16384), C=obuf [pos][c]
        dim3 gpv(CCH / 128, NTOK / 128, NFRM);    // (4, 8, 16)
        mfma_gemm<EPI_PV><<<gpv, 256, 0, stream>>>((const u16*)sbuf, vt, obuf, nullptr,
                                                   nullptr, flag,
                                                   2 * NTOK, NPOS, CCH, NTOK,
                                                   2L * NTOK * NTOK, NTOK, (long)NTOK * CCH);
    } else {
        for (int f = 0; f < NFRM; ++f) {
            dim3 gsc(NTOK / 128, NTOK / 128, 1);
            mfma_gemm<EPI_SC><<<gsc, 256, 0, stream>>>(
                qt + (size_t)f * NTOK * CCH, kt + (size_t)f * NTOK * CCH, sbuf,
                nullptr, nullptr, flag, CCH, CCH, NTOK, CCH, 0, 0, 0);
            softmax_rows_bf16<<<NTOK, 256, 0, stream>>>(sbuf);
            dim3 gpv(CCH / 128, NTOK / 128, 1);
            mfma_gemm<EPI_PV><<<gpv, 256, 0, stream>>>(
                (const u16*)sbuf, vt + (size_t)f * NTOK, obuf + (size_t)f * NTOK * CCH,
                nullptr, nullptr, flag, 2 * NTOK, NPOS, CCH, NTOK, 0, 0, 0);
        }
    }

    // out: C[cout][pos] = Wo . O + bo + x, poly store
    dim3 go(NPOS / 128, CCH / 128, 1);    // (128, 4)
    mfma_gemm<EPI_OUT><<<go, 256, 0, stream>>>(cw[3], obuf, d_out, cb[3], x, flag,
                                               CCH, CCH, NPOS, CCH, 0, 0, 0);
}

// Round 5
// 312.639 us; speedup vs baseline: 3.9300x; 1.3515x over previous
//
#include <hip/hip_runtime.h>
#include <hip/hip_bf16.h>

// Shapes fixed by the reference: b=1, c=512, t=16, h=w=32
#define CCH   512
#define NPOS  16384
#define NTOK  1024
#define NFRM  16
#define NGRP  32
#define GSZ   (CCH / NGRP)
#define GELEM (GSZ * NPOS)
#define GN_SPLIT 32                 // stage-1 blocks per group

typedef unsigned short u16;
typedef unsigned int   u32;
typedef __attribute__((ext_vector_type(8))) short  short8;
typedef __attribute__((ext_vector_type(4))) float  floatx4;

__device__ __forceinline__ float bf2f(u16 u) {
    return __uint_as_float(((u32)u) << 16);
}
__device__ __forceinline__ u16 f2bf(float f) {
    u32 u = __float_as_uint(f);
    u = (u + 0x7fffu + ((u >> 16) & 1u)) >> 16;
    return (u16)u;
}
__device__ __forceinline__ float ldx(const void* p, size_t i, bool f32m) {
    return f32m ? ((const float*)p)[i] : bf2f(((const u16*)p)[i]);
}

// ------------------------------------------------------------ dtype detect
__launch_bounds__(256)
__global__ void detect_dtype(const u32* __restrict__ x32, u32* __restrict__ flag) {
    __shared__ int cnt;
    if (threadIdx.x == 0) cnt = 0;
    __syncthreads();
    int c = 0;
    for (int i = threadIdx.x; i < 4096; i += 256) {
        u32 v = x32[i] & 0xFFFFu;
        u32 e = (v >> 7) & 0xFFu;
        if (e >= 0xC8u) c++;
    }
    atomicAdd(&cnt, c);
    __syncthreads();
    if (threadIdx.x == 0) *flag = (cnt > 64) ? 1u : 0u;
}

__launch_bounds__(256)
__global__ void conv_bf16(const void* __restrict__ src, u16* __restrict__ dst,
                          int n, const u32* __restrict__ flag) {
    bool f32m = *flag != 0u;
    int i = blockIdx.x * 256 + threadIdx.x;
    if (i < n) dst[i] = f32m ? f2bf(((const float*)src)[i]) : ((const u16*)src)[i];
}

// ------------------------------------------------- GroupNorm stage 1: partials
// grid = NGRP * GN_SPLIT blocks; each reduces GELEM/GN_SPLIT contiguous elems.
__launch_bounds__(256)
__global__ void gn_partial(const void* __restrict__ x, float2* __restrict__ partials,
                           const u32* __restrict__ flag) {
    __shared__ float sm[8];
    bool f32m = *flag != 0u;
    const int chunk = GELEM / GN_SPLIT;           // 8192 elements
    size_t base = (size_t)blockIdx.x * chunk;
    float s = 0.f, ss = 0.f;
    if (f32m) {
        const float4* p = (const float4*)((const float*)x + base);
        for (int i = threadIdx.x; i < chunk / 4; i += 256) {
            float4 u = p[i];
            s  += u.x + u.y + u.z + u.w;
            ss += u.x * u.x + u.y * u.y + u.z * u.z + u.w * u.w;
        }
    } else {
        const ushort4* p = (const ushort4*)((const u16*)x + base);
        for (int i = threadIdx.x; i < chunk / 4; i += 256) {
            ushort4 u = p[i];
            float a = bf2f(u.x), b = bf2f(u.y), c = bf2f(u.z), d = bf2f(u.w);
            s  += a + b + c + d;
            ss += a * a + b * b + c * c + d * d;
        }
    }
    int lane = threadIdx.x & 63, w = threadIdx.x >> 6;
    float t = s;
    #pragma unroll
    for (int o = 32; o > 0; o >>= 1) t += __shfl_down(t, o, 64);
    if (lane == 0) sm[w] = t;
    t = ss;
    #pragma unroll
    for (int o = 32; o > 0; o >>= 1) t += __shfl_down(t, o, 64);
    if (lane == 0) sm[4 + w] = t;
    __syncthreads();
    if (threadIdx.x == 0)
        partials[blockIdx.x] = make_float2(sm[0] + sm[1] + sm[2] + sm[3],
                                           sm[4] + sm[5] + sm[6] + sm[7]);
}

// stage 2: fold partials per group, emit per-channel affine (xn = x*sc + sh)
__launch_bounds__(256)
__global__ void gn_coef(const float2* __restrict__ partials, const void* __restrict__ gamma,
                        const void* __restrict__ beta, float2* __restrict__ coef,
                        const u32* __restrict__ flag) {
    bool f32m = *flag != 0u;
    int c = blockIdx.x * 256 + threadIdx.x;
    if (c < CCH) {
        int g = c >> 4;
        float sum = 0.f, sq = 0.f;
        #pragma unroll
        for (int i = 0; i < GN_SPLIT; ++i) {
            float2 p = partials[g * GN_SPLIT + i];
            sum += p.x; sq += p.y;
        }
        float mean = sum * (1.0f / (float)GELEM);
        float var  = fmaxf(sq * (1.0f / (float)GELEM) - mean * mean, 0.0f);
        float rstd = rsqrtf(var + 1e-6f);
        float gm = ldx(gamma, c, f32m), b = ldx(beta, c, f32m);
        float sc = rstd * gm;
        coef[c] = make_float2(sc, b - mean * sc);
    }
}

// GN-apply + transpose: x [c][pos] (poly) -> xn_t [pos][c] (bf16)
__launch_bounds__(256)
__global__ void gn_apply_t(const void* __restrict__ x, const float2* __restrict__ coef,
                           u16* __restrict__ xt, const u32* __restrict__ flag) {
    bool f32m = *flag != 0u;
    __shared__ float tile[64][65];
    int p0 = blockIdx.x * 64, c0 = blockIdx.y * 64;
    int lane = threadIdx.x & 63, rg = threadIdx.x >> 6;
    #pragma unroll 4
    for (int i = 0; i < 16; ++i) {
        int row = rg * 16 + i;          // channel offset within tile
        int c = c0 + row;
        float2 cf = coef[c];
        float v = ldx(x, (size_t)c * NPOS + p0 + lane, f32m);
        tile[row][lane] = v * cf.x + cf.y;
    }
    __syncthreads();
    #pragma unroll 4
    for (int i = 0; i < 16; ++i) {
        int prow = rg * 16 + i;         // position offset within tile
        xt[(size_t)(p0 + prow) * CCH + c0 + lane] = f2bf(tile[lane][prow]);
    }
}

// --------------------------------------------------------- MFMA TN GEMM
// C[m][n] = sum_k A[m*lda+k] * B[n*ldb+k]   (A,B bf16, K-contiguous rows)
// 128x128 tile / workgroup (4 waves, 64x64 each), BK=32, 16x16x32 bf16 MFMA.
#define EPI_QK  0   // C bf16, += bias[n]
#define EPI_V   1   // C bf16, += bias[m]
#define EPI_SC  2   // C f32,  *= scale
#define EPI_PV  3   // C bf16
#define EPI_OUT 4   // C poly, += bias[m] + resid[idx]

#define LDS_ROW 40  // BK(32) + 8 pad, in bf16 elements

template<int EPI>
__launch_bounds__(256)
__global__ void mfma_gemm(const u16* __restrict__ A, const u16* __restrict__ B,
                          void* __restrict__ C, const u16* __restrict__ bias,
                          const void* __restrict__ resid, const u32* __restrict__ flag,
                          int lda, int ldb, int ldc, int K,
                          long aFS, long bFS, long cFS) {
    __shared__ u16 As[128 * LDS_ROW];
    __shared__ u16 Bs[128 * LDS_ROW];
    const int tid = threadIdx.x;
    const int f = blockIdx.z;
    const u16* Ab = A + (size_t)f * aFS + (size_t)blockIdx.y * 128 * lda;
    const u16* Bb = B + (size_t)f * bFS + (size_t)blockIdx.x * 128 * ldb;

    const int srow = tid >> 2;            // 0..63
    const int sch  = (tid & 3) * 8;       // 0,8,16,24 (bf16 elems)

    const int wave = tid >> 6, lane = tid & 63;
    const int wm = (wave >> 1) * 64, wn = (wave & 1) * 64;
    const int l15 = lane & 15, quad = lane >> 4;

    floatx4 acc[4][4] = {};

    for (int kk = 0; kk < K; kk += 32) {
        uint4 a0 = *(const uint4*)(Ab + (size_t)srow * lda + kk + sch);
        uint4 a1 = *(const uint4*)(Ab + (size_t)(srow + 64) * lda + kk + sch);
        uint4 b0 = *(const uint4*)(Bb + (size_t)srow * ldb + kk + sch);
        uint4 b1 = *(const uint4*)(Bb + (size_t)(srow + 64) * ldb + kk + sch);
        __syncthreads();
        *(uint4*)&As[srow * LDS_ROW + sch]        = a0;
        *(uint4*)&As[(srow + 64) * LDS_ROW + sch] = a1;
        *(uint4*)&Bs[srow * LDS_ROW + sch]        = b0;
        *(uint4*)&Bs[(srow + 64) * LDS_ROW + sch] = b1;
        __syncthreads();
        short8 af[4], bf[4];
        #pragma unroll
        for (int mi = 0; mi < 4; ++mi)
            af[mi] = *(const short8*)&As[(wm + mi * 16 + l15) * LDS_ROW + quad * 8];
        #pragma unroll
        for (int ni = 0; ni < 4; ++ni)
            bf[ni] = *(const short8*)&Bs[(wn + ni * 16 + l15) * LDS_ROW + quad * 8];
        #pragma unroll
        for (int mi = 0; mi < 4; ++mi)
            #pragma unroll
            for (int ni = 0; ni < 4; ++ni)
                acc[mi][ni] = __builtin_amdgcn_mfma_f32_16x16x32_bf16(
                    af[mi], bf[ni], acc[mi][ni], 0, 0, 0);
    }

    const bool f32m = (EPI == EPI_OUT) ? (*flag != 0u) : false;
    const int m_base = blockIdx.y * 128 + wm;
    const int n_base = blockIdx.x * 128 + wn;
    const float scale = 0.044194173824159216f;  // 512^-0.5

    #pragma unroll
    for (int mi = 0; mi < 4; ++mi) {
        #pragma unroll
        for (int ni = 0; ni < 4; ++ni) {
            int n = n_base + ni * 16 + l15;
            float bn = (EPI == EPI_QK) ? bf2f(bias[n]) : 0.0f;
            #pragma unroll
            for (int r = 0; r < 4; ++r) {
                int m = m_base + mi * 16 + quad * 4 + r;
                float v = acc[mi][ni][r];
                size_t idx = (size_t)f * cFS + (size_t)m * ldc + n;
                if (EPI == EPI_QK) {
                    ((u16*)C)[idx] = f2bf(v + bn);
                } else if (EPI == EPI_V) {
                    ((u16*)C)[idx] = f2bf(v + bf2f(bias[m]));
                } else if (EPI == EPI_SC) {
                    ((float*)C)[idx] = v * scale;
                } else if (EPI == EPI_PV) {
                    ((u16*)C)[idx] = f2bf(v);
                } else {  // EPI_OUT
                    float r2 = v + bf2f(bias[m]) + ldx(resid, idx, f32m);
                    if (f32m) ((float*)C)[idx] = r2;
                    else      ((u16*)C)[idx]   = f2bf(r2);
                }
            }
        }
    }
}

// softmax over rows of 1024 f32, writing bf16 P in-place at row start
__launch_bounds__(256)
__global__ void softmax_rows_bf16(float* __restrict__ S) {
    __shared__ float sm[8];
    float* p = S + (size_t)blockIdx.x * NTOK;
    u16* pb = (u16*)p;
    int tid = threadIdx.x;
    float v0 = p[tid], v1 = p[tid + 256], v2 = p[tid + 512], v3 = p[tid + 768];
    float m = fmaxf(fmaxf(v0, v1), fmaxf(v2, v3));
    int lane = tid & 63, w = tid >> 6;
    #pragma unroll
    for (int o = 32; o > 0; o >>= 1) m = fmaxf(m, __shfl_down(m, o, 64));
    if (lane == 0) sm[w] = m;
    __syncthreads();
    m = fmaxf(fmaxf(sm[0], sm[1]), fmaxf(sm[2], sm[3]));
    v0 = __expf(v0 - m); v1 = __expf(v1 - m);
    v2 = __expf(v2 - m); v3 = __expf(v3 - m);
    float s = v0 + v1 + v2 + v3;
    #pragma unroll
    for (int o = 32; o > 0; o >>= 1) s += __shfl_down(s, o, 64);
    if (lane == 0) sm[4 + w] = s;
    __syncthreads();
    s = sm[4] + sm[5] + sm[6] + sm[7];
    float inv = 1.0f / s;
    __syncthreads();   // all reads complete before bf16 overwrite
    pb[tid]       = f2bf(v0 * inv);
    pb[tid + 256] = f2bf(v1 * inv);
    pb[tid + 512] = f2bf(v2 * inv);
    pb[tid + 768] = f2bf(v3 * inv);
}

// ---------------------------------------------------------------- launcher
extern "C" void kernel_launch(void* const* d_in, const int* in_sizes, int n_in,
                              void* d_out, int out_size, void* d_ws, size_t ws_size,
                              hipStream_t stream) {
    const void* x   = d_in[0];
    const void* gam = d_in[1];
    const void* bet = d_in[2];

    // Workspace layout:
    //   [0,4K)  coef   [4K,+8K) gn partials (1024 float2)  [12352) flag
    //   [16K, +2MiB)   canonical bf16 weights wq,wk,wv,wo
    //   [~2.1Mi, +4KiB) canonical bf16 biases
    //   [4Mi)   xn_t (16Mi)  -- reused as obuf after V-projection
    //   [20Mi)  qt   (16Mi)
    //   [36Mi)  kt   (16Mi)
    //   [52Mi)  vt   (16Mi)
    //   [68Mi)  sbuf: 64Mi f32 (big) or 4Mi (per-frame fallback)
    char* ws = (char*)d_ws;
    float2* coef     = (float2*)(ws);
    float2* partials = (float2*)(ws + 4096);               // 1024 float2 = 8KiB
    u32*    flag     = (u32*)(ws + 12352);
    u16* cw[4] = { (u16*)(ws + 16384),              (u16*)(ws + 16384 +  524288ull),
                   (u16*)(ws + 16384 + 1048576ull), (u16*)(ws + 16384 + 1572864ull) };
    u16* cb[4] = { (u16*)(ws + 2113536ull),        (u16*)(ws + 2113536ull + 1024),
                   (u16*)(ws + 2113536ull + 2048), (u16*)(ws + 2113536ull + 3072) };
    u16*  xnt  = (u16*)(ws + (4ull  << 20));
    u16*  qt   = (u16*)(ws + (20ull << 20));
    u16*  kt   = (u16*)(ws + (36ull << 20));
    u16*  vt   = (u16*)(ws + (52ull << 20));
    float* sbuf = (float*)(ws + (68ull << 20));
    u16*  obuf = xnt;

    const size_t need_big = (68ull << 20) + (64ull << 20) + 4096;
    const bool big = ws_size >= need_big;

    detect_dtype<<<1, 256, 0, stream>>>((const u32*)x, flag);
    for (int i = 0; i < 4; ++i) {
        conv_bf16<<<1024, 256, 0, stream>>>(d_in[3 + 2 * i], cw[i], 262144, flag);
        conv_bf16<<<2, 256, 0, stream>>>(d_in[4 + 2 * i], cb[i], 512, flag);
    }
    gn_partial<<<NGRP * GN_SPLIT, 256, 0, stream>>>(x, partials, flag);
    gn_coef<<<2, 256, 0, stream>>>(partials, gam, bet, coef, flag);
    gn_apply_t<<<dim3(NPOS / 64, CCH / 64), 256, 0, stream>>>(x, coef, xnt, flag);

    // q,k: C[pos][cout], A=xn_t (lda=512), B=W (ldb=512), ldc=512
    dim3 gqk(CCH / 128, NPOS / 128, 1);   // (4, 128)
    mfma_gemm<EPI_QK><<<gqk, 256, 0, stream>>>(xnt, cw[0], qt, cb[0], nullptr, flag,
                                               CCH, CCH, CCH, CCH, 0, 0, 0);
    mfma_gemm<EPI_QK><<<gqk, 256, 0, stream>>>(xnt, cw[1], kt, cb[1], nullptr, flag,
                                               CCH, CCH, CCH, CCH, 0, 0, 0);
    // v: C[cout][pos], A=Wv (lda=512), B=xn_t (ldb=512), ldc=16384
    dim3 gv(NPOS / 128, CCH / 128, 1);    // (128, 4)
    mfma_gemm<EPI_V><<<gv, 256, 0, stream>>>(cw[2], xnt, vt, cb[2], nullptr, flag,
                                             CCH, CCH, NPOS, CCH, 0, 0, 0);

    if (big) {
        // scores: per frame, C f32 [i][j], A=qt, B=kt
        dim3 gsc(NTOK / 128, NTOK / 128, NFRM);   // (8, 8, 16)
        mfma_gemm<EPI_SC><<<gsc, 256, 0, stream>>>(qt, kt, sbuf, nullptr, nullptr, flag,
                                                   CCH, CCH, NTOK, CCH,
                                                   NTOK * CCH, NTOK * CCH, (long)NTOK * NTOK);
        softmax_rows_bf16<<<NFRM * NTOK, 256, 0, stream>>>(sbuf);
        // pv: A=P (bf16 view of sbuf, lda=2048), B=vt rows=c (ldb=16384), C=obuf [pos][c]
        dim3 gpv(CCH / 128, NTOK / 128, NFRM);    // (4, 8, 16)
        mfma_gemm<EPI_PV><<<gpv, 256, 0, stream>>>((const u16*)sbuf, vt, obuf, nullptr,
                                                   nullptr, flag,
                                                   2 * NTOK, NPOS, CCH, NTOK,
                                                   2L * NTOK * NTOK, NTOK, (long)NTOK * CCH);
    } else {
        for (int f = 0; f < NFRM; ++f) {
            dim3 gsc(NTOK / 128, NTOK / 128, 1);
            mfma_gemm<EPI_SC><<<gsc, 256, 0, stream>>>(
                qt + (size_t)f * NTOK * CCH, kt + (size_t)f * NTOK * CCH, sbuf,
                nullptr, nullptr, flag, CCH, CCH, NTOK, CCH, 0, 0, 0);
            softmax_rows_bf16<<<NTOK, 256, 0, stream>>>(sbuf);
            dim3 gpv(CCH / 128, NTOK / 128, 1);
            mfma_gemm<EPI_PV><<<gpv, 256, 0, stream>>>(
                (const u16*)sbuf, vt + (size_t)f * NTOK, obuf + (size_t)f * NTOK * CCH,
                nullptr, nullptr, flag, 2 * NTOK, NPOS, CCH, NTOK, 0, 0, 0);
        }
    }

    // out: C[cout][pos] = Wo . O + bo + x, poly store
    dim3 go(NPOS / 128, CCH / 128, 1);    // (128, 4)
    mfma_gemm<EPI_OUT><<<go, 256, 0, stream>>>(cw[3], obuf, d_out, cb[3], x, flag,
                                               CCH, CCH, NPOS, CCH, 0, 0, 0);
}